// Round 6
// baseline (24.304 us; speedup 1.0000x reference)
//
#include <hip/hip_runtime.h>

// 8-qubit effective circuit (reference qubits 8..10 stay |0>).
// 1 batch element per wave; physical index i in [0,256): i = lane*4 + j.
// CNOT ring layers tracked as GF(2) relabeling T_m = P^m (never executed).
// RY on logical bit b at layer m = XOR-butterfly with physical mask
// M = T_m^{-1} e_b, sign parity(row_b(T_m) & i).
// ALL cross-lane ops are VALU: DPP (quad_perm/mirror/ror) for xor masks <16,
// v_permlane16/32_swap for xor 16/32 -- no ds_bpermute anywhere.
// permlane swaps hardened: explicit movs into earlyclobber outs (no aliasing),
// s_nop guards (VALU->permlane wait-state hazard), and a^b^x combine (exact,
// and correct under either possible swap direction).

namespace {

struct M8 { unsigned r[8]; };

constexpr M8 kI{{0x01,0x02,0x04,0x08,0x10,0x20,0x40,0x80}};
constexpr M8 kP{{0xFF,0xFE,0xFC,0xF8,0xF0,0xE0,0xC0,0x7F}};
constexpr M8 kQ{{0x03,0x06,0x0C,0x18,0x30,0x60,0xC1,0x81}};

constexpr M8 mul(const M8& A, const M8& B) {
  M8 C{{0,0,0,0,0,0,0,0}};
  for (int j = 0; j < 8; ++j) {
    unsigned by = 0;
    for (int b = 0; b < 8; ++b) by |= ((B.r[b] >> j) & 1u) << b;
    for (int b = 0; b < 8; ++b) {
      unsigned v = A.r[b] & by;
      v ^= v >> 4; v ^= v >> 2; v ^= v >> 1;
      C.r[b] |= (v & 1u) << j;
    }
  }
  return C;
}

constexpr bool eqI(const M8& A) {
  bool e = true;
  for (int b = 0; b < 8; ++b) e = e && (A.r[b] == (1u << b));
  return e;
}

struct Tables { unsigned Mm[21][8]; unsigned Rr[21][8]; bool ok; };

constexpr Tables build() {
  Tables t{};
  M8 T = kI, Ti = kI;
  bool ok = eqI(mul(kP, kQ)) && eqI(mul(kQ, kP));
  for (int m = 0; m <= 20; ++m) {
    ok = ok && eqI(mul(T, Ti));
    for (int b = 0; b < 8; ++b) {
      unsigned mm = 0;
      for (int k = 0; k < 8; ++k) mm |= ((Ti.r[k] >> b) & 1u) << k;
      t.Mm[m][b] = mm;
      t.Rr[m][b] = T.r[b];
    }
    T = mul(kP, T);
    Ti = mul(Ti, kQ);
  }
  t.ok = ok;
  return t;
}

constexpr Tables kT = build();
static_assert(kT.ok, "GF(2) inverse tracking failed");

// ---- cross-lane xor cost (VALU instructions per register) ----
constexpr int dppc(unsigned l) {
  if (l == 0u) return 0;
  if (l == 1u || l == 2u || l == 3u || l == 7u || l == 8u || l == 15u) return 1;
  return 2;
}
constexpr int xc(unsigned L) {
  return ((L & 32u) ? 3 : 0) + ((L & 16u) ? 3 : 0) + dppc(L & 15u);
}

constexpr int single_cost(int m, int a) { return 4 * xc(kT.Mm[m][a] >> 2) + 10; }
constexpr int pair_cost(int m, int a, int b) {
  const unsigned LA = kT.Mm[m][a] >> 2, LB = kT.Mm[m][b] >> 2, LC = LA ^ LB;
  int c = xc(LA);
  if (LB != LA) c += xc(LB);
  if (LC != LA && LC != LB) c += xc(LC);
  return 4 * c + 18;
}

struct AllPlans { int nops[21]; int pa[21][8]; int pb[21][8]; };

// Bitmask DP over "gates already scheduled" — O(256*8) per layer, far below
// the constexpr step limit (the exhaustive matching recursion was not).
constexpr AllPlans build_plans() {
  AllPlans ap{};
  for (int m = 0; m < 21; ++m) {
    int sc[8] = {};
    int pc[8][8] = {};
    for (int a = 0; a < 8; ++a) {
      sc[a] = single_cost(m, a);
      for (int b = a + 1; b < 8; ++b) pc[a][b] = pair_cost(m, a, b);
    }
    int dp[256] = {};
    int chb[256] = {};
    for (int used = 254; used >= 0; --used) {
      int a = 0;
      while ((used >> a) & 1) ++a;
      int best = dp[used | (1 << a)] + sc[a];
      int bb = -1;
      for (int b = a + 1; b < 8; ++b) {
        if ((used >> b) & 1) continue;
        const int c = dp[used | (1 << a) | (1 << b)] + pc[a][b];
        if (c < best) { best = c; bb = b; }
      }
      dp[used] = best;
      chb[used] = bb;
    }
    int used = 0, n = 0;
    while (used != 255) {
      int a = 0;
      while ((used >> a) & 1) ++a;
      const int bb = chb[used];
      ap.pa[m][n] = a;
      ap.pb[m][n] = bb;
      used |= 1 << a;
      if (bb >= 0) used |= 1 << bb;
      ++n;
    }
    ap.nops[m] = n;
    for (int k = n; k < 8; ++k) { ap.pa[m][k] = 0; ap.pb[m][k] = -1; }
  }
  return ap;
}

constexpr AllPlans kPlans = build_plans();

constexpr bool plans_ok() {
  for (int m = 0; m < 21; ++m) {
    unsigned mask = 0; int cnt = 0;
    for (int k = 0; k < kPlans.nops[m]; ++k) {
      mask |= 1u << kPlans.pa[m][k]; ++cnt;
      if (kPlans.pb[m][k] >= 0) { mask |= 1u << kPlans.pb[m][k]; ++cnt; }
    }
    if (mask != 0xFFu || cnt != 8) return false;
  }
  return true;
}
static_assert(plans_ok(), "bad gate schedule");

__constant__ AllPlans dPlans = build_plans();

// ---- VALU xor-shuffle ----
constexpr int dpp1(unsigned l) {
  return l == 1u ? 0xB1 : l == 2u ? 0x4E : l == 3u ? 0x1B :
         l == 7u ? 0x141 : l == 8u ? 0x128 : l == 15u ? 0x140 : -1;
}
constexpr unsigned fstep(unsigned l) {
  switch (l) {
    case 4u: return 3u;  case 5u: return 2u;  case 6u: return 1u;
    case 9u: return 1u;  case 10u: return 2u; case 11u: return 3u;
    case 12u: return 3u; case 13u: return 2u; case 14u: return 1u;
  }
  return 0u;
}

// x[lane^16] via v_permlane16_swap: with both operands = x, the two results
// hold {x[lane], x[lane^16]} at every lane (under either swap direction), so
// a ^ b ^ x == x[lane^16] exactly. movs into earlyclobber outputs prevent
// operand aliasing; s_nops cover the VALU-write -> permlane-read wait states.
__device__ __forceinline__ int swap16(int x) {
  int a, b;
  asm volatile("v_mov_b32 %0, %2\n\t"
               "v_mov_b32 %1, %2\n\t"
               "s_nop 1\n\t"
               "v_permlane16_swap_b32 %0, %1\n\t"
               "s_nop 1"
               : "=&v"(a), "=&v"(b) : "v"(x));
  return a ^ b ^ x;
}
__device__ __forceinline__ int swap32(int x) {
  int a, b;
  asm volatile("v_mov_b32 %0, %2\n\t"
               "v_mov_b32 %1, %2\n\t"
               "s_nop 1\n\t"
               "v_permlane32_swap_b32 %0, %1\n\t"
               "s_nop 1"
               : "=&v"(a), "=&v"(b) : "v"(x));
  return a ^ b ^ x;
}

template<unsigned L>
__device__ __forceinline__ float xshfl(float v, int lane) {
  if constexpr (L == 0u) {
    return v;
  } else {
    int x = __float_as_int(v);
    constexpr unsigned low = L & 15u;
    if constexpr (low != 0u) {
      constexpr int c1 = dpp1(low);
      if constexpr (c1 >= 0) {
        x = __builtin_amdgcn_update_dpp(x, x, c1, 0xF, 0xF, false);
      } else {
        constexpr unsigned f = fstep(low);
        constexpr int ca = dpp1(f);
        constexpr int cb = dpp1(low ^ f);
        x = __builtin_amdgcn_update_dpp(x, x, ca, 0xF, 0xF, false);
        x = __builtin_amdgcn_update_dpp(x, x, cb, 0xF, 0xF, false);
      }
    }
    if constexpr (L & 16u) x = swap16(x);
    if constexpr (L & 32u) x = swap32(x);
    (void)lane;
    return __int_as_float(x);
  }
}

struct LaneSet { unsigned L[3]; };
constexpr LaneSet lane_set(unsigned a, unsigned b, unsigned c) {
  LaneSet r{{0,0,0}}; int n = 0;
  const unsigned v[3] = {a, b, c};
  for (int i = 0; i < 3; ++i) {
    if (!v[i]) continue;
    bool dup = false;
    for (int j = 0; j < n; ++j) if (r.L[j] == v[i]) dup = true;
    if (!dup) r.L[n++] = v[i];
  }
  return r;
}

template<unsigned RX, int IDX>
__device__ __forceinline__ float pick(const float (&s)[4], const float (&t0)[4],
                                      const float (&t1)[4], const float (&t2)[4], int j) {
  if constexpr (IDX == 0) return t0[j ^ (int)RX];
  else if constexpr (IDX == 1) return t1[j ^ (int)RX];
  else if constexpr (IDX == 2) return t2[j ^ (int)RX];
  else return s[j ^ (int)RX];
}

template<int m, int op>
__device__ __forceinline__ void do_op(int lane, const float4* __restrict__ ct4, float (&s)[4]) {
  constexpr int ga = kPlans.pa[m][op];
  constexpr int gb = kPlans.pb[m][op];
  constexpr unsigned MA = kT.Mm[m][ga];
  constexpr unsigned RA = kT.Rr[m][ga];
  constexpr unsigned LA = MA >> 2;
  const float4 k = ct4[m * 8 + op];
  const int sa = __popc((int)(RA >> 2) & lane) & 1;

  if constexpr (gb < 0) {
    float tA[4];
    #pragma unroll
    for (int j = 0; j < 4; ++j) tA[j] = xshfl<LA>(s[j ^ (int)(MA & 3u)], lane);
    const float wa = sa ? -k.y : k.y;
    float ns[4];
    #pragma unroll
    for (int j = 0; j < 4; ++j) {
      const float va = (__popc((int)(RA & 3u) & j) & 1) ? -wa : wa;
      ns[j] = fmaf(va, tA[j], k.x * s[j]);
    }
    #pragma unroll
    for (int j = 0; j < 4; ++j) s[j] = ns[j];
  } else {
    constexpr int gb2 = (gb < 0) ? 0 : gb;
    constexpr unsigned MB = kT.Mm[m][gb2], MC = MA ^ MB;
    constexpr unsigned RB = kT.Rr[m][gb2];
    constexpr unsigned LB = MB >> 2, LC = MC >> 2;
    constexpr LaneSet LS = lane_set(LA, LB, LC);
    constexpr unsigned L1 = LS.L[0], L2 = LS.L[1], L3 = LS.L[2];
    constexpr int iA = (LA == 0) ? -1 : (LA == L1 ? 0 : (LA == L2 ? 1 : 2));
    constexpr int iB = (LB == 0) ? -1 : (LB == L1 ? 0 : (LB == L2 ? 1 : 2));
    constexpr int iC = (LC == 0) ? -1 : (LC == L1 ? 0 : (LC == L2 ? 1 : 2));

    float b1[4], b2[4], b3[4];
    if constexpr (L1 != 0) {
      #pragma unroll
      for (int j = 0; j < 4; ++j) b1[j] = xshfl<L1>(s[j], lane);
    }
    if constexpr (L2 != 0) {
      #pragma unroll
      for (int j = 0; j < 4; ++j) b2[j] = xshfl<L2>(s[j], lane);
    }
    if constexpr (L3 != 0) {
      #pragma unroll
      for (int j = 0; j < 4; ++j) b3[j] = xshfl<L3>(s[j], lane);
    }

    const int sb = __popc((int)(RB >> 2) & lane) & 1;
    const float wa = sa ? -k.y : k.y;
    const float wb = sb ? -k.z : k.z;
    const float wc = (sa ^ sb) ? -k.w : k.w;

    float ns[4];
    #pragma unroll
    for (int j = 0; j < 4; ++j) {
      const int pa_ = __popc((int)(RA & 3u) & j) & 1;
      const int pb_ = __popc((int)(RB & 3u) & j) & 1;
      const float vA = pa_ ? -wa : wa;
      const float vB = pb_ ? -wb : wb;
      const float vC = (pa_ ^ pb_) ? -wc : wc;
      ns[j] = fmaf(vC, pick<MC & 3u, iC>(s, b1, b2, b3, j),
              fmaf(vB, pick<MB & 3u, iB>(s, b1, b2, b3, j),
              fmaf(vA, pick<MA & 3u, iA>(s, b1, b2, b3, j), k.x * s[j])));
    }
    #pragma unroll
    for (int j = 0; j < 4; ++j) s[j] = ns[j];
  }
}

template<int m, int op>
__device__ __forceinline__ void run_ops(int lane, const float4* __restrict__ ct4, float (&s)[4]) {
  if constexpr (op < kPlans.nops[m]) {
    do_op<m, op>(lane, ct4, s);
    run_ops<m, op + 1>(lane, ct4, s);
  }
}

template<int m>
__device__ __forceinline__ void run_all(int lane, const float4* __restrict__ ct4, float (&s)[4]) {
  if constexpr (m <= 20) {
    run_ops<m, 0>(lane, ct4, s);
    run_all<m + 1>(lane, ct4, s);
  }
}

template<unsigned MK>
__device__ __forceinline__ void red_stage(float (&a)[8], int lane) {
  #pragma unroll
  for (int B = 0; B < 8; ++B) a[B] += xshfl<MK>(a[B], lane);
}

}  // namespace

__global__ __launch_bounds__(256) void qae_kernel(const float* __restrict__ x,
                                                  const float* __restrict__ theta,
                                                  float* __restrict__ out) {
  __shared__ float4 ct4[168];  // [21 layers][8 op slots]
  const int t = threadIdx.x;
  if (t < 168) {
    const int m = t >> 3, op = t & 7;
    if (op < dPlans.nops[m]) {
      const int ga = dPlans.pa[m][op], gb = dPlans.pb[m][op];
      float sA, cA;
      sincosf(theta[m * 8 + (7 - ga)] * 0.5f, &sA, &cA);
      if (gb >= 0) {
        float sB, cB;
        sincosf(theta[m * 8 + (7 - gb)] * 0.5f, &sB, &cB);
        ct4[t] = make_float4(cA * cB, sA * cB, cA * sB, sA * sB);
      } else {
        ct4[t] = make_float4(cA, sA, 0.f, 0.f);
      }
    }
  }
  __syncthreads();

  const int lane = t & 63;
  const int b = blockIdx.x * 4 + (t >> 6);

  const float4 xv = *reinterpret_cast<const float4*>(x + (size_t)b * 256 + lane * 4);
  float s[4] = {xv.x, xv.y, xv.z, xv.w};

  run_all<0>(lane, ct4, s);

  // output bucket B = logical bits 0..2 (parities of rows of T_20)
  constexpr unsigned R0 = kT.Rr[20][0], R1 = kT.Rr[20][1], R2 = kT.Rr[20][2];
  const int q0 = __popc((int)(R0 >> 2) & lane) & 1;
  const int q1 = __popc((int)(R1 >> 2) & lane) & 1;
  const int q2 = __popc((int)(R2 >> 2) & lane) & 1;

  float acc[8];
  #pragma unroll
  for (int B = 0; B < 8; ++B) acc[B] = 0.f;
  #pragma unroll
  for (int j = 0; j < 4; ++j) {
    const int bj = (q0 ^ (__popc((int)(R0 & 3u) & j) & 1))
                 | ((q1 ^ (__popc((int)(R1 & 3u) & j) & 1)) << 1)
                 | ((q2 ^ (__popc((int)(R2 & 3u) & j) & 1)) << 2);
    const float pj = s[j] * s[j];
    #pragma unroll
    for (int B = 0; B < 8; ++B) acc[B] += (bj == B) ? pj : 0.f;
  }
  red_stage<1>(acc, lane);
  red_stage<2>(acc, lane);
  red_stage<4>(acc, lane);
  red_stage<8>(acc, lane);
  red_stage<16>(acc, lane);
  red_stage<32>(acc, lane);

  if (lane == 0) {
    float4* o = reinterpret_cast<float4*>(out + (size_t)b * 8);
    o[0] = make_float4(acc[0], acc[1], acc[2], acc[3]);
    o[1] = make_float4(acc[4], acc[5], acc[6], acc[7]);
  }
}

extern "C" void kernel_launch(void* const* d_in, const int* in_sizes, int n_in,
                              void* d_out, int out_size, void* d_ws, size_t ws_size,
                              hipStream_t stream) {
  const float* x = (const float*)d_in[0];      // [1024, 256]
  const float* theta = (const float*)d_in[1];  // [168]
  float* out = (float*)d_out;                  // [1024, 8]
  qae_kernel<<<256, 256, 0, stream>>>(x, theta, out);
}

// Round 7
// 19.552 us; speedup vs baseline: 1.2431x; 1.2431x over previous
//
#include <hip/hip_runtime.h>

// 8-qubit effective state (qubits 8..10 of the reference stay |000>).
// Layout: batch element -> one wave (64 lanes); index i in [0,256):
//   i = lane*4 + j, lane = i[7:2], j = i[1:0]  (i bit b corresponds to
//   qubit q = 7-b of the reference).
// RY(q) pairs amplitudes differing in bit (7-q); CNOT ring q -> (q+1)%8.
//
// NOTE (rounds 2-6 post-mortem): depth-reduced (84-stage), DP-planned, and
// all-VALU DPP/permlane variants of this kernel all measured SLOWER or equal
// (19.7 / 21.1 / 22.6 / 24.3 us) despite 3-5x lower modeled body cost.
// Wall time is dominated by fixed launch/graph-replay overhead; this simplest
// variant is the best-measured kernel. Resubmitted byte-identical as a
// repeatability probe.

#define N_ANGLES 168  // (M+1)*NV = 21*8

__device__ __forceinline__ void ry_layer(int lane, const float* __restrict__ tb,
                                         float& s0, float& s1, float& s2, float& s3) {
    // q = 0..5 : bit = 7-q, lane bit lb = 5-q  -> cross-lane
    #pragma unroll
    for (int q = 0; q < 6; ++q) {
        const float cv = tb[2 * q];
        const float sv = tb[2 * q + 1];
        const int lb = 5 - q;
        const int mask = 1 << lb;
        const float sg = ((lane >> lb) & 1) ? -sv : sv;
        const float p0 = __shfl_xor(s0, mask);
        const float p1 = __shfl_xor(s1, mask);
        const float p2 = __shfl_xor(s2, mask);
        const float p3 = __shfl_xor(s3, mask);
        s0 = cv * s0 + sg * p0;
        s1 = cv * s1 + sg * p1;
        s2 = cv * s2 + sg * p2;
        s3 = cv * s3 + sg * p3;
    }
    // q = 6 : bit 1 (local), pairs (0,2) and (1,3)
    {
        const float cv = tb[12], sv = tb[13];
        const float n0 = cv * s0 + sv * s2;
        const float n2 = cv * s2 - sv * s0;
        const float n1 = cv * s1 + sv * s3;
        const float n3 = cv * s3 - sv * s1;
        s0 = n0; s1 = n1; s2 = n2; s3 = n3;
    }
    // q = 7 : bit 0 (local), pairs (0,1) and (2,3)
    {
        const float cv = tb[14], sv = tb[15];
        const float n0 = cv * s0 + sv * s1;
        const float n1 = cv * s1 - sv * s0;
        const float n2 = cv * s2 + sv * s3;
        const float n3 = cv * s3 - sv * s2;
        s0 = n0; s1 = n1; s2 = n2; s3 = n3;
    }
}

__global__ __launch_bounds__(256) void qae_kernel(const float* __restrict__ x,
                                                  const float* __restrict__ theta,
                                                  float* __restrict__ out) {
    __shared__ float tab[N_ANGLES * 2];  // interleaved (cos, sin) of theta/2
    const int t = threadIdx.x;
    if (t < N_ANGLES) {
        const float a = theta[t] * 0.5f;
        tab[2 * t]     = cosf(a);
        tab[2 * t + 1] = sinf(a);
    }
    __syncthreads();

    const int lane = t & 63;
    const int wave = t >> 6;
    const int b = blockIdx.x * 4 + wave;

    const float4 xv = *reinterpret_cast<const float4*>(x + (size_t)b * 256 + lane * 4);
    float s0 = xv.x, s1 = xv.y, s2 = xv.z, s3 = xv.w;

    #pragma unroll
    for (int m = 0; m < 20; ++m) {
        const float* tb = &tab[m * 16];
        ry_layer(lane, tb, s0, s1, s2, s3);

        // CNOT ring: control qubit q (bit 7-q) -> target qubit (q+1)%8 (bit 6-q / 7)
        // q = 0..4 : control lane bit (5-q), target lane bit (4-q)
        #pragma unroll
        for (int q = 0; q < 5; ++q) {
            const int cb = 5 - q;
            const int tmask = 1 << (4 - q);
            const bool cond = (lane >> cb) & 1;
            const float p0 = __shfl_xor(s0, tmask);
            const float p1 = __shfl_xor(s1, tmask);
            const float p2 = __shfl_xor(s2, tmask);
            const float p3 = __shfl_xor(s3, tmask);
            s0 = cond ? p0 : s0;
            s1 = cond ? p1 : s1;
            s2 = cond ? p2 : s2;
            s3 = cond ? p3 : s3;
        }
        // q = 5 : control lane bit 0 (i bit 2), target i bit 1 (local) -> swap (s0,s2),(s1,s3)
        {
            const bool cond = lane & 1;
            const float t0 = s0, t1 = s1;
            s0 = cond ? s2 : s0;
            s2 = cond ? t0 : s2;
            s1 = cond ? s3 : s1;
            s3 = cond ? t1 : s3;
        }
        // q = 6 : control i bit 1, target i bit 0 -> swap s2<->s3
        {
            const float tt = s2; s2 = s3; s3 = tt;
        }
        // q = 7 : control i bit 0 (local), target i bit 7 (lane bit 5)
        s1 = __shfl_xor(s1, 32);
        s3 = __shfl_xor(s3, 32);
    }

    // final RY layer (angles 160..167)
    ry_layer(lane, &tab[320], s0, s1, s2, s3);

    // probs_B[b][B] = sum_{i % 8 == B} amp^2 ; B = (lane&1)*4 + j
    float p0 = s0 * s0, p1 = s1 * s1, p2 = s2 * s2, p3 = s3 * s3;
    #pragma unroll
    for (int m = 2; m <= 32; m <<= 1) {
        p0 += __shfl_xor(p0, m);
        p1 += __shfl_xor(p1, m);
        p2 += __shfl_xor(p2, m);
        p3 += __shfl_xor(p3, m);
    }
    if (lane < 2) {
        *reinterpret_cast<float4*>(out + (size_t)b * 8 + lane * 4) =
            make_float4(p0, p1, p2, p3);
    }
}

extern "C" void kernel_launch(void* const* d_in, const int* in_sizes, int n_in,
                              void* d_out, int out_size, void* d_ws, size_t ws_size,
                              hipStream_t stream) {
    const float* x = (const float*)d_in[0];      // [1024, 256]
    const float* theta = (const float*)d_in[1];  // [168]
    float* out = (float*)d_out;                  // [1024, 8]

    // 1024 batch elements, 4 per block (one per wave)
    qae_kernel<<<256, 256, 0, stream>>>(x, theta, out);
}